// Round 10
// baseline (312.011 us; speedup 1.0000x reference)
//
#include <hip/hip_runtime.h>
#include <hip/hip_bf16.h>
#include <cstddef>

#define B_   256
#define P_   196
#define DE_  2048
#define DD_  512
#define DA_  512
#define M_   (B_*P_)   // 50176

#define BM   64
#define KT   32
#define NKT  (DE_/KT)  // 64

typedef __attribute__((ext_vector_type(4))) float f32x4;
typedef __attribute__((ext_vector_type(8))) short s16x8;

static __device__ __forceinline__ short f2bf(float x) {
    __hip_bfloat16 h = __float2bfloat16(x);
    return *reinterpret_cast<short*>(&h);
}

#define GLOAD_LDS16(g, l) __builtin_amdgcn_global_load_lds( \
    (const __attribute__((address_space(1))) void*)(g),     \
    (__attribute__((address_space(3))) void*)(l), 16, 0, 0)

// ---------------------------------------------------------------------------
// Kernel 0: pack W_enc [K][N] fp32 -> bf16 per-fragment layout (proven r5-r7):
//   unit u = (kt*32 + gf)*64 + lane (16 B each);
//   lane l, j -> W[kt*32 + (l>>4)*8 + j][gf*16 + (l&15)]
// ---------------------------------------------------------------------------
__global__ __launch_bounds__(256) void pack_wenc(
        const float* __restrict__ W, __hip_bfloat16* __restrict__ out) {
    __shared__ float lds[KT][DA_];          // 64 KB
    const int kt = blockIdx.x;
    const int t  = threadIdx.x;
#pragma unroll
    for (int i = 0; i < 64; ++i) {
        int e = i * 256 + t;
        int k = e >> 9, n = e & 511;
        lds[k][n] = W[(size_t)(kt * KT + k) * DA_ + n];
    }
    __syncthreads();
    short* o = reinterpret_cast<short*>(out) + (size_t)kt * (32 * 64 * 8);
#pragma unroll
    for (int i = 0; i < 8; ++i) {
        int idx  = i * 256 + t;
        int gf   = idx >> 6;
        int lane = idx & 63;
        int g = lane >> 4, c = lane & 15;
        s16x8 w;
#pragma unroll
        for (int j = 0; j < 8; ++j)
            w[j] = f2bf(lds[g * 8 + j][gf * 16 + c]);
        *reinterpret_cast<s16x8*>(o + (size_t)idx * 8) = w;
    }
}

// ---------------------------------------------------------------------------
// Kernel 1: att2p[b][a] = dh[b,:] @ W_dec[:,a] + b_dec[a] + b_enc[a]
// ---------------------------------------------------------------------------
__global__ __launch_bounds__(512) void att2_kernel(
        const float* __restrict__ dh, const float* __restrict__ W_dec,
        const float* __restrict__ b_dec, const float* __restrict__ b_enc,
        float* __restrict__ att2p) {
    __shared__ float s_dh[DD_];
    const int b = blockIdx.x;
    const int a = threadIdx.x;
    s_dh[a] = dh[(size_t)b * DD_ + a];
    __syncthreads();
    float acc = 0.f;
#pragma unroll 8
    for (int k = 0; k < DD_; ++k)
        acc += s_dh[k] * W_dec[(size_t)k * DA_ + a];
    att2p[(size_t)b * DA_ + a] = acc + b_dec[a] + b_enc[a];
}

// ---------------------------------------------------------------------------
// Kernel 2: GEMM 50176x512x2048, tile 64x256 (nh split), 4 waves (64x64 each).
// Never-drain pipeline: A fp32 via global_load_lds into 4-deep LDS ring
// (issued 2 steps ahead); B L2->VGPR 2-set (issued 2 steps ahead, after its
// set's MFMAs). One s_barrier per K-step preceded by s_waitcnt vmcnt(6):
// queue [A(t+1):2, A(t+2):2, B(t+2):4] -> retires A(t+1), keeps 6 in flight.
// No sched_barrier, no lgkm asm, no vmcnt(0) until the epilogue syncthreads.
// ---------------------------------------------------------------------------
__global__ __launch_bounds__(256, 3) void gemm_att(
        const float* __restrict__ enc, const __hip_bfloat16* __restrict__ Bp,
        const float* __restrict__ att2p, const float* __restrict__ Wfull,
        float* __restrict__ att0, float* __restrict__ att1) {
    __shared__ float a_lds[4][BM * KT];     // 4 x 8 KB fp32 ring
    __shared__ float red[BM][4];            // 1 KB

    const int tid  = threadIdx.x;
    const int wave = tid >> 6;
    const int lane = tid & 63;
    const int g    = lane >> 4;
    const int c    = lane & 15;

    const int p   = blockIdx.x;
    const int mt_ = (p >> 4) * 8 + (p & 7);   // 0..783
    const int nh  = (p >> 3) & 1;             // N-half; pair is 8 bids apart
    const int block_row = mt_ * BM;

    // A staging: 2 units/thread: u = i*256+tid -> row u>>3, dest slot u&7,
    // source slot (u&7)^(row&7); row&7 == (tid>>3)&7 for both i.
    const int arow  = tid >> 3;
    const int aslot = (tid & 7) ^ (arow & 7);
    const float* a_src = enc + (size_t)(block_row + arow) * DE_ + aslot * 4;

    // A frag read: row rr = mt*16+c, k-slots 2g,2g+1 stored XOR (rr&7)=(c&7)
    const int ax  = c & 7;
    const int ao0 = ((2 * g)     ^ ax) * 4;
    const int ao1 = ((2 * g + 1) ^ ax) * 4;

    // B frags (16 B units): frag (t, n) at ((t*32 + nh*16 + wave*4 + n)*64 + lane)
    const s16x8* bp = reinterpret_cast<const s16x8*>(Bp)
                    + ((size_t)(nh * 16 + wave * 4)) * 64 + lane;

    f32x4 acc[4][4] = {};
    s16x8 bfX[4], bfY[4];

#define ISSUE_A(T) do {                                                  \
        const int tt_ = (T) > 63 ? 63 : (T);                             \
        float* d_ = a_lds[(T) & 3];                                      \
        GLOAD_LDS16(a_src + tt_ * KT,                 &d_[tid * 4]);     \
        GLOAD_LDS16(a_src + (size_t)32 * DE_ + tt_ * KT, &d_[(256 + tid) * 4]); \
    } while (0)

#define LOAD_B(dst, T) do {                                              \
        const int tt_ = (T) > 63 ? 63 : (T);                             \
        _Pragma("unroll")                                                \
        for (int n_ = 0; n_ < 4; ++n_)                                   \
            dst[n_] = bp[((size_t)tt_ * 32 + n_) * 64];                  \
    } while (0)

#define COMPUTE(T, bfr) do {                                             \
        const float* ab_ = a_lds[(T) & 3];                               \
        s16x8 af[4];                                                     \
        _Pragma("unroll")                                                \
        for (int mt2 = 0; mt2 < 4; ++mt2) {                              \
            const float* base_ = ab_ + (mt2 * 16 + c) * KT;              \
            f32x4 v0_ = *reinterpret_cast<const f32x4*>(base_ + ao0);    \
            f32x4 v1_ = *reinterpret_cast<const f32x4*>(base_ + ao1);    \
            s16x8 w_;                                                    \
            w_[0]=f2bf(v0_.x); w_[1]=f2bf(v0_.y); w_[2]=f2bf(v0_.z); w_[3]=f2bf(v0_.w); \
            w_[4]=f2bf(v1_.x); w_[5]=f2bf(v1_.y); w_[6]=f2bf(v1_.z); w_[7]=f2bf(v1_.w); \
            af[mt2] = w_;                                                \
        }                                                                \
        _Pragma("unroll")                                                \
        for (int nt2 = 0; nt2 < 4; ++nt2)                                \
            _Pragma("unroll")                                            \
            for (int mt2 = 0; mt2 < 4; ++mt2)                            \
                acc[mt2][nt2] = __builtin_amdgcn_mfma_f32_16x16x32_bf16( \
                                    af[mt2], bfr[nt2], acc[mt2][nt2], 0, 0, 0); \
    } while (0)

#define WAIT6_BAR() do {                                                 \
        asm volatile("s_waitcnt vmcnt(6)" ::: "memory");                 \
        __builtin_amdgcn_s_barrier();                                    \
    } while (0)

    // ---- prologue: order fixes FIFO so vmcnt(6) leaves A(1)+B(1) in flight
    LOAD_B(bfX, 0);          // 4
    ISSUE_A(0);              // 2
    ISSUE_A(1);              // 2
    LOAD_B(bfY, 1);          // 4  -> queue: B0,A0,A1,B1 ; vmcnt(6) retires B0,A0
    WAIT6_BAR();

#pragma clang loop unroll(disable)
    for (int t = 0; t < NKT; t += 2) {
        // even: compute A(t) x B(t)=bfX
        ISSUE_A(t + 2);
        COMPUTE(t, bfX);
        LOAD_B(bfX, t + 2);          // after bfX's last MFMA (WAR = issue-only)
        WAIT6_BAR();                 // retires A(t+1); leaves A(t+2)+B(t+2)
        // odd: compute A(t+1) x B(t+1)=bfY
        ISSUE_A(t + 3);
        COMPUTE(t + 1, bfY);
        LOAD_B(bfY, t + 3);
        WAIT6_BAR();                 // retires A(t+2), B(t+2)
    }

    // ---- fused epilogue: partial relu-dot over this block's 256 cols ----
    const int b0    = block_row / P_;
    const int b1    = min(b0 + 1, B_ - 1);
    const int split = (b0 + 1) * P_;
    const int ncol0 = nh * 256 + wave * 64;
    float wf[4], a20[4], a21[4];
#pragma unroll
    for (int nt = 0; nt < 4; ++nt) {
        const int n = ncol0 + nt * 16 + c;
        wf[nt]  = Wfull[n];
        a20[nt] = att2p[(size_t)b0 * DA_ + n];
        a21[nt] = att2p[(size_t)b1 * DA_ + n];
    }
#pragma unroll
    for (int mt = 0; mt < 4; ++mt) {
#pragma unroll
        for (int q = 0; q < 4; ++q) {
            const int row_local = mt * 16 + g * 4 + q;
            const int R = block_row + row_local;
            const bool hiB = (R >= split);
            float s = 0.f;
#pragma unroll
            for (int nt = 0; nt < 4; ++nt) {
                float a2 = hiB ? a21[nt] : a20[nt];
                float v  = acc[mt][nt][q] + a2;
                v = fmaxf(v, 0.f);
                s += v * wf[nt];
            }
#pragma unroll
            for (int off = 1; off < 16; off <<= 1)
                s += __shfl_xor(s, off, 64);
            if (c == 0) red[row_local][wave] = s;
        }
    }
    __syncthreads();     // full drain (also retires tail junk loads)
    if (tid < BM) {
        float t = red[tid][0] + red[tid][1] + red[tid][2] + red[tid][3];
        float* dst = nh ? att1 : att0;
        dst[block_row + tid] = t;
    }
#undef ISSUE_A
#undef LOAD_B
#undef COMPUTE
#undef WAIT6_BAR
}

// ---------------------------------------------------------------------------
// Kernel 3: softmax over P per batch -> alpha (att = att0 + att1)
// ---------------------------------------------------------------------------
__global__ __launch_bounds__(256) void softmax_kernel(
        const float* __restrict__ att0, const float* __restrict__ att1,
        float* __restrict__ alpha) {
    const int b = blockIdx.x;
    const int t = threadIdx.x;
    __shared__ float sred[4];
    float v = -1e30f;
    if (t < P_) v = att0[(size_t)b * P_ + t] + att1[(size_t)b * P_ + t];
    float m = v;
#pragma unroll
    for (int off = 1; off < 64; off <<= 1) m = fmaxf(m, __shfl_xor(m, off, 64));
    if ((t & 63) == 0) sred[t >> 6] = m;
    __syncthreads();
    const float mall = fmaxf(fmaxf(sred[0], sred[1]), fmaxf(sred[2], sred[3]));
    __syncthreads();
    float e = (t < P_) ? expf(v - mall) : 0.f;
    float s = e;
#pragma unroll
    for (int off = 1; off < 64; off <<= 1) s += __shfl_xor(s, off, 64);
    if ((t & 63) == 0) sred[t >> 6] = s;
    __syncthreads();
    const float stot = sred[0] + sred[1] + sred[2] + sred[3];
    if (t < P_) alpha[(size_t)b * P_ + t] = e / stot;
}

// ---------------------------------------------------------------------------
// Kernel 4: context[b][e] = sum_p alpha[b][p] * enc[b][p][e]
// ---------------------------------------------------------------------------
__global__ __launch_bounds__(256) void context_kernel(
        const float* __restrict__ enc, const float* __restrict__ alpha,
        float* __restrict__ ctx) {
    const int b = blockIdx.x;
    const int e = blockIdx.y * 1024 + threadIdx.x * 4;
    __shared__ float s_alpha[P_];
    if (threadIdx.x < P_) s_alpha[threadIdx.x] = alpha[(size_t)b * P_ + threadIdx.x];
    __syncthreads();
    f32x4 acc = {0.f, 0.f, 0.f, 0.f};
    const float* base = enc + (size_t)b * P_ * DE_ + e;
#pragma unroll 4
    for (int p = 0; p < P_; ++p) {
        f32x4 v = *reinterpret_cast<const f32x4*>(base + (size_t)p * DE_);
        acc += s_alpha[p] * v;
    }
    *reinterpret_cast<f32x4*>(ctx + (size_t)b * DE_ + e) = acc;
}

// ---------------------------------------------------------------------------
extern "C" void kernel_launch(void* const* d_in, const int* in_sizes, int n_in,
                              void* d_out, int out_size, void* d_ws, size_t ws_size,
                              hipStream_t stream) {
    const float* enc    = (const float*)d_in[0];
    const float* dh     = (const float*)d_in[1];
    const float* W_enc  = (const float*)d_in[2];
    const float* b_enc  = (const float*)d_in[3];
    const float* W_dec  = (const float*)d_in[4];
    const float* b_dec  = (const float*)d_in[5];
    const float* W_full = (const float*)d_in[6];

    float* out       = (float*)d_out;
    float* ctx_out   = out;                       // [B,DE]
    float* alpha_out = out + (size_t)B_ * DE_;    // [B,P]

    char* ws = (char*)d_ws;
    __hip_bfloat16* Bp = (__hip_bfloat16*)ws;                         // 2 MB
    float* att2p = (float*)(ws + 2u * 1024 * 1024);                   // 512 KB
    float* att0  = (float*)(ws + 2u * 1024 * 1024 + 512u * 1024);     // 200 KB
    float* att1  = att0 + M_;                                         // 200 KB

    pack_wenc     <<<NKT,            256, 0, stream>>>(W_enc, Bp);
    att2_kernel   <<<B_,             512, 0, stream>>>(dh, W_dec, b_dec, b_enc, att2p);
    gemm_att      <<<2 * (M_ / BM),  256, 0, stream>>>(enc, Bp, att2p, W_full, att0, att1);
    softmax_kernel<<<B_,             256, 0, stream>>>(att0, att1, alpha_out);
    context_kernel<<<dim3(B_, 2),    256, 0, stream>>>(enc, alpha_out, ctx_out);
}